// Round 6
// baseline (574.971 us; speedup 1.0000x reference)
//
#include <hip/hip_runtime.h>
#include <hip/hip_fp8.h>

typedef unsigned char u8;
typedef float v2f __attribute__((ext_vector_type(2)));

#define SCAN_B 256

// bucketed scatter params
#define NPB      128          // dst nodes per bucket
#define NPB_SH   7
#define P2_CAP   6144         // win entries per bucket (48 KB LDS)
#define STG_CAP  6144         // fixed staging capacity per bucket (expected max ~5.4K)
#define P1_CHUNK 32768        // edges per part1 block (long runs -> full-line writebacks)
#define P1_T     512
#define NB_MAX   2048         // part1 LDS bucket capacity (NB=1172 for N=150K)
#define STG_OFF  ((size_t)10 << 20)   // staging offset in d_out (x0 uses [0, 9.6MB))

static __device__ __forceinline__ float fp8_to_f32(u8 b) {
    __hip_fp8_e4m3 t;
    t.__x = (__hip_fp8_storage_t)b;
    return (float)t;
}
static __device__ __forceinline__ u8 f32_to_fp8(float v) {
    __hip_fp8_e4m3 t(v);
    return (u8)t.__x;
}

// hardware packed fp8->f32 (2 values per instruction)
template <bool HI>
static __device__ __forceinline__ v2f pk2(unsigned w) {
#if __has_builtin(__builtin_amdgcn_cvt_pk_f32_fp8)
    return __builtin_amdgcn_cvt_pk_f32_fp8((int)w, HI);
#else
    v2f r;
    r.x = fp8_to_f32(HI ? (u8)(w >> 16) : (u8)(w));
    r.y = fp8_to_f32(HI ? (u8)(w >> 24) : (u8)(w >> 8));
    return r;
#endif
}

// ---------------- edge-format probe: int64-as-int32 (odd words zero) vs int32 ----------------
__global__ void detect_kernel(const int* __restrict__ edges, int* __restrict__ flag) {
    __shared__ int cnt[256];
    int t = threadIdx.x;
    int c = 0;
    for (int i = t; i < 32768; i += 256)
        if (edges[2 * i + 1] != 0) c++;
    cnt[t] = c;
    __syncthreads();
    for (int off = 128; off > 0; off >>= 1) {
        if (t < off) cnt[t] += cnt[t + off];
        __syncthreads();
    }
    if (t == 0) flag[0] = (cnt[0] < 8) ? 2 : 1;
}

// ---------------- fixed staging cursors: gcur[b] = b * STG_CAP ----------------
__global__ void gcur_fixed_init(int* __restrict__ gcur, int NB) {
    int b = blockIdx.x * blockDim.x + threadIdx.x;
    if (b < NB) gcur[b] = b * STG_CAP;
}

// ---------------- part1: partition edges into fixed-capacity dst-bucket regions --------
// 32K edges/block -> ~28-entry (112B) runs per (block,bucket); packed u32 entries
// (sv | dv_local<<20). Long aligned-ish runs keep lines exclusive to one block -> near
// full-line writebacks; 4x fewer gcur claim atomics than 8K chunks.
__global__ void part1_kernel(const int* __restrict__ edges, const int* __restrict__ flag,
                             int* __restrict__ gcur, unsigned* __restrict__ staging,
                             int E, int NB) {
    __shared__ int lcount[NB_MAX];
    __shared__ int lbase[NB_MAX];
    int t = threadIdx.x;
    int s = flag[0];
    long e0 = (long)blockIdx.x * P1_CHUNK;
    for (int b = t; b < NB; b += P1_T) lcount[b] = 0;
    __syncthreads();
    for (int j = 0; j < P1_CHUNK / P1_T; ++j) {
        long e = e0 + (long)j * P1_T + t;
        if (e < E) {
            int dv = edges[(long)E * s + e * s];
            atomicAdd(&lcount[dv >> NPB_SH], 1);
        }
    }
    __syncthreads();
    for (int b = t; b < NB; b += P1_T) {
        int c = lcount[b];
        lbase[b] = (c > 0) ? atomicAdd(&gcur[b], c) : 0;
        lcount[b] = 0;          // reuse as block-local cursor
    }
    __syncthreads();
    for (int j = 0; j < P1_CHUNK / P1_T; ++j) {
        long e = e0 + (long)j * P1_T + t;
        if (e < E) {
            int sv = edges[e * s];
            int dv = edges[(long)E * s + e * s];
            int b = dv >> NPB_SH;
            int slot = atomicAdd(&lcount[b], 1);
            int pos = lbase[b] + slot;
            if (pos < (b + 1) * STG_CAP)            // overflow guard (never hit here)
                staging[pos] = (unsigned)sv | ((unsigned)(dv & (NPB - 1)) << 20);
        }
    }
}

// ---------------- bucket scan: bbase = excl-scan of (gcur[b] - b*STG_CAP) ----------------
__global__ void bucket_scan_kernel(const int* __restrict__ gcur, int* __restrict__ bbase,
                                   int NB) {
    __shared__ int sh[2][1024];
    int t = threadIdx.x;
    int i0 = 2 * t, i1 = 2 * t + 1;
    int a0 = (i0 < NB) ? (gcur[i0] - i0 * STG_CAP) : 0;
    int a1 = (i1 < NB) ? (gcur[i1] - i1 * STG_CAP) : 0;
    sh[0][t] = a0 + a1;
    __syncthreads();
    int src = 0;
    for (int off = 1; off < 1024; off <<= 1) {
        int x = sh[src][t] + ((t >= off) ? sh[src][t - off] : 0);
        sh[src ^ 1][t] = x;
        src ^= 1;
        __syncthreads();
    }
    int incl = sh[src][t];           // inclusive over pairs
    int excl = incl - (a0 + a1);
    if (i0 < NB) bbase[i0] = excl;
    if (i1 < NB) bbase[i1] = excl + a0;
    if (t == 1023) bbase[NB] = incl; // total == E
}

// ---------------- part2a: per-bucket node degrees -> row_ptr + dis (LDS only) ------------
__global__ void __launch_bounds__(256) part2a_kernel(
        const int* __restrict__ gcur, const int* __restrict__ bbase,
        const unsigned* __restrict__ staging, int* __restrict__ row_ptr,
        float* __restrict__ dis, int n, int E, int NB) {
    __shared__ int cnt[NPB];
    __shared__ int sc[2][NPB];
    int b = blockIdx.x;
    int t = threadIdx.x;
    int dlo = b << NPB_SH;
    int sbase = b * STG_CAP;
    int c = gcur[b] - sbase;         // edges in this bucket
    int base = bbase[b];             // CSR base of bucket
    if (t < NPB) cnt[t] = 0;
    __syncthreads();
    for (int k = t; k < c; k += 256) {
        unsigned wd = staging[sbase + k];
        atomicAdd(&cnt[wd >> 20], 1);
    }
    __syncthreads();
    if (t < NPB) sc[0][t] = cnt[t];
    __syncthreads();
    int src = 0;
    for (int off = 1; off < NPB; off <<= 1) {
        if (t < NPB) {
            int x = sc[src][t] + ((t >= off) ? sc[src][t - off] : 0);
            sc[src ^ 1][t] = x;
        }
        src ^= 1;
        __syncthreads();
    }
    if (t < NPB) {
        int node = dlo + t;
        if (node < n) {
            int d = cnt[t];
            row_ptr[node] = base + sc[src][t] - d;   // exclusive
            dis[node] = (d > 0) ? rsqrtf((float)d) : 0.0f;
        }
    }
    if (b == 0 && t == 0) row_ptr[n] = E;
}

// ---------------- part2b: per-bucket exact CSR placement, built in LDS ----------------
__global__ void __launch_bounds__(256) part2b_kernel(
        const int* __restrict__ row_ptr, const int* __restrict__ gcur,
        const unsigned* __restrict__ staging, const float* __restrict__ dis,
        int2* __restrict__ cw, int n) {
    __shared__ int2 win[P2_CAP];
    __shared__ int cur[NPB];
    int b = blockIdx.x;
    int t = threadIdx.x;
    int dlo = b << NPB_SH;
    int sbase = b * STG_CAP;
    int cnt = gcur[b] - sbase;
    int base = row_ptr[dlo];
    if (t < NPB) {
        int node = dlo + t;
        cur[t] = (node < n) ? (row_ptr[node] - base) : 0;
    }
    __syncthreads();
    if (cnt <= P2_CAP) {
        for (int k = t; k < cnt; k += 256) {
            unsigned wd = staging[sbase + k];
            int sv = wd & 0xFFFFF;
            int dloc = wd >> 20;
            float w = dis[sv] * dis[dlo + dloc];
            int p = atomicAdd(&cur[dloc], 1);
            win[p] = make_int2(sv, __float_as_int(w));
        }
        __syncthreads();
        for (int k = t; k < cnt; k += 256)
            cw[base + k] = win[k];
    } else {
        for (int k = t; k < cnt; k += 256) {
            unsigned wd = staging[sbase + k];
            int sv = wd & 0xFFFFF;
            int dloc = wd >> 20;
            float w = dis[sv] * dis[dlo + dloc];
            int p = atomicAdd(&cur[dloc], 1);
            cw[base + p] = make_int2(sv, __float_as_int(w));
        }
    }
}

// ================= legacy fallback path (NB > NB_MAX / N too big / staging misfit) =======
__global__ void count_deg_kernel(const int* __restrict__ edges, const int* __restrict__ flag,
                                 int* __restrict__ deg, int E) {
    int e = blockIdx.x * blockDim.x + threadIdx.x;
    if (e >= E) return;
    int s = flag[0];
    int d = edges[(long)E * s + (long)e * s];
    atomicAdd(&deg[d], 1);
}

__global__ void scan_phase1(const int* __restrict__ deg, int* __restrict__ row_ptr,
                            int* __restrict__ bsum, int n) {
    __shared__ int sh[2][SCAN_B];
    int t = threadIdx.x;
    int gi = blockIdx.x * SCAN_B + t;
    int v = (gi < n) ? deg[gi] : 0;
    int src = 0;
    sh[0][t] = v;
    __syncthreads();
    for (int off = 1; off < SCAN_B; off <<= 1) {
        int x = sh[src][t] + ((t >= off) ? sh[src][t - off] : 0);
        sh[src ^ 1][t] = x;
        src ^= 1;
        __syncthreads();
    }
    int incl = sh[src][t];
    if (gi < n) row_ptr[gi] = incl - v;
    if (t == SCAN_B - 1) bsum[blockIdx.x] = incl;
}

__global__ void scan_phase2(int* __restrict__ bsum, int nb) {
    __shared__ int sh[1024];
    int t = threadIdx.x;
    sh[t] = (t < nb) ? bsum[t] : 0;
    __syncthreads();
    if (t == 0) {
        int acc = 0;
        for (int i = 0; i < nb; ++i) { int x = sh[i]; sh[i] = acc; acc += x; }
    }
    __syncthreads();
    if (t < nb) bsum[t] = sh[t];
}

__global__ void scan_phase3(const int* __restrict__ deg, const int* __restrict__ bsum,
                            int* __restrict__ row_ptr, int* __restrict__ cursor,
                            float* __restrict__ dis, int n, int E) {
    int gi = blockIdx.x * SCAN_B + threadIdx.x;
    if (gi < n) {
        int e = row_ptr[gi] + bsum[blockIdx.x];
        row_ptr[gi] = e;
        cursor[gi]  = e;
        int d = deg[gi];
        dis[gi] = (d > 0) ? rsqrtf((float)d) : 0.0f;
    }
    if (gi == 0) row_ptr[n] = E;
}

__global__ void scatter_kernel(const int* __restrict__ edges, const int* __restrict__ flag,
                               const float* __restrict__ dis, int* __restrict__ cursor,
                               int2* __restrict__ cw, int E) {
    int e = blockIdx.x * blockDim.x + threadIdx.x;
    if (e >= E) return;
    int s = flag[0];
    int sv = edges[(long)e * s];
    int dv = edges[(long)E * s + (long)e * s];
    float w = dis[sv] * dis[dv];
    int pos = atomicAdd(&cursor[dv], 1);
    cw[pos] = make_int2(sv, __float_as_int(w));
}
// ================= end legacy =================

// ---------------- init: x0 (fp8, in d_out scratch) = emb ----------------
__global__ void init_kernel(const float* __restrict__ eu, const float* __restrict__ ei,
                            u8* __restrict__ x0, long NU64, long tot) {
    long i = (long)blockIdx.x * blockDim.x + threadIdx.x;
    if (i >= tot) return;
    float v = (i < NU64) ? eu[i] : ei[i - NU64];
    x0[i] = f32_to_fp8(v);
}

// ---------------- SpMM layer: one wave per dst node, 8 edges per gather instruction ------
// g = lane>>3 selects one of 8 edge slots, h = lane&7 the dim-octet (dims 8h..8h+7, one
// dwordx2 of fp8). Each gather instruction serves 8 edges (512B across 8 lines).
__global__ void spmm_kernel(const int* __restrict__ row_ptr, const int2* __restrict__ cw,
                            const u8* __restrict__ xin, u8* __restrict__ xout, int n) {
    int wave = (blockIdx.x * blockDim.x + threadIdx.x) >> 6;
    int lane = threadIdx.x & 63;
    if (wave >= n) return;
    int beg = row_ptr[wave], end = row_ptr[wave + 1];
    int g = lane >> 3;      // edge slot 0..7
    int h = lane & 7;       // dim octet

    float a0 = 0.f, a1 = 0.f, a2 = 0.f, a3 = 0.f;
    float a4 = 0.f, a5 = 0.f, a6 = 0.f, a7 = 0.f;

    for (int iA = beg + g; iA < end; iA += 16) {
        int iB = iA + 8;
        bool vB = iB < end;

        int2 ca = cw[iA];
        int2 cb = cw[vB ? iB : iA];

        uint2 dA = *(const uint2*)(xin + ((long)ca.x << 6) + (h << 3));
        uint2 dB = *(const uint2*)(xin + ((long)cb.x << 6) + (h << 3));

        float wA = __int_as_float(ca.y);
        float wB = vB ? __int_as_float(cb.y) : 0.0f;

        v2f pA0 = pk2<false>(dA.x), pA1 = pk2<true>(dA.x);
        v2f pA2 = pk2<false>(dA.y), pA3 = pk2<true>(dA.y);
        v2f pB0 = pk2<false>(dB.x), pB1 = pk2<true>(dB.x);
        v2f pB2 = pk2<false>(dB.y), pB3 = pk2<true>(dB.y);

        a0 = fmaf(wA, pA0.x, a0); a1 = fmaf(wA, pA0.y, a1);
        a2 = fmaf(wA, pA1.x, a2); a3 = fmaf(wA, pA1.y, a3);
        a4 = fmaf(wA, pA2.x, a4); a5 = fmaf(wA, pA2.y, a5);
        a6 = fmaf(wA, pA3.x, a6); a7 = fmaf(wA, pA3.y, a7);
        a0 = fmaf(wB, pB0.x, a0); a1 = fmaf(wB, pB0.y, a1);
        a2 = fmaf(wB, pB1.x, a2); a3 = fmaf(wB, pB1.y, a3);
        a4 = fmaf(wB, pB2.x, a4); a5 = fmaf(wB, pB2.y, a5);
        a6 = fmaf(wB, pB3.x, a6); a7 = fmaf(wB, pB3.y, a7);
    }

    a0 += __shfl_xor(a0, 8);  a1 += __shfl_xor(a1, 8);
    a2 += __shfl_xor(a2, 8);  a3 += __shfl_xor(a3, 8);
    a4 += __shfl_xor(a4, 8);  a5 += __shfl_xor(a5, 8);
    a6 += __shfl_xor(a6, 8);  a7 += __shfl_xor(a7, 8);
    a0 += __shfl_xor(a0, 16); a1 += __shfl_xor(a1, 16);
    a2 += __shfl_xor(a2, 16); a3 += __shfl_xor(a3, 16);
    a4 += __shfl_xor(a4, 16); a5 += __shfl_xor(a5, 16);
    a6 += __shfl_xor(a6, 16); a7 += __shfl_xor(a7, 16);
    a0 += __shfl_xor(a0, 32); a1 += __shfl_xor(a1, 32);
    a2 += __shfl_xor(a2, 32); a3 += __shfl_xor(a3, 32);
    a4 += __shfl_xor(a4, 32); a5 += __shfl_xor(a5, 32);
    a6 += __shfl_xor(a6, 32); a7 += __shfl_xor(a7, 32);

    if (g == 0) {
        unsigned lo = (unsigned)f32_to_fp8(a0)
                    | ((unsigned)f32_to_fp8(a1) << 8)
                    | ((unsigned)f32_to_fp8(a2) << 16)
                    | ((unsigned)f32_to_fp8(a3) << 24);
        unsigned hi = (unsigned)f32_to_fp8(a4)
                    | ((unsigned)f32_to_fp8(a5) << 8)
                    | ((unsigned)f32_to_fp8(a6) << 16)
                    | ((unsigned)f32_to_fp8(a7) << 24);
        *(uint2*)(xout + ((long)wave << 6) + (h << 3)) = make_uint2(lo, hi);
    }
}

// ---------------- epilogue ----------------
__global__ void final_kernel(const u8* __restrict__ x1, const u8* __restrict__ x2,
                             const u8* __restrict__ x3, const u8* __restrict__ x4,
                             const float* __restrict__ eu, const float* __restrict__ ei,
                             float* __restrict__ out, long NU64, long NI64) {
    long i = (long)blockIdx.x * blockDim.x + threadIdx.x;
    if (i >= NU64 + NI64) return;
    float base = (i < NU64) ? eu[i] : ei[i - NU64];
    float s = base + fp8_to_f32(x1[i]) + fp8_to_f32(x2[i])
                   + fp8_to_f32(x3[i]) + fp8_to_f32(x4[i]);
    float v = s * (1.0f / 25.0f);
    if (i < NU64) {
        out[i] = v;
        out[NU64 + i] = base;
    } else {
        long j = i - NU64;
        out[2 * NU64 + j] = v;
        out[2 * NU64 + NI64 + j] = base;
    }
}

extern "C" void kernel_launch(void* const* d_in, const int* in_sizes, int n_in,
                              void* d_out, int out_size, void* d_ws, size_t ws_size,
                              hipStream_t stream) {
    const float* eu = (const float*)d_in[0];
    const float* ei = (const float*)d_in[1];
    const int* edges = (const int*)d_in[2];
    float* out = (float*)d_out;

    const int NU = in_sizes[0] / 64;
    const int NI = in_sizes[1] / 64;
    const int N  = NU + NI;
    const int E  = in_sizes[2] / 2;
    const int NB = (N + NPB - 1) / NPB;     // 1172 for N=150K

    // workspace carve-up (256B aligned)
    char* w = (char*)d_ws;
    size_t off = 0;
    auto alloc = [&](size_t bytes) -> void* {
        void* p = w + off;
        off += (bytes + 255) & ~(size_t)255;
        return p;
    };
    int*   flag    = (int*)  alloc(256);
    int*   deg     = (int*)  alloc((size_t)N * 4);        // legacy path only
    int*   row_ptr = (int*)  alloc((size_t)(N + 1) * 4);
    int*   cursor  = (int*)  alloc((size_t)N * 4);        // legacy path only
    float* dis     = (float*)alloc((size_t)N * 4);
    int*   bsum    = (int*)  alloc(1024 * 4);             // legacy path only
    int*   gcur    = (int*)  alloc((size_t)(NB + 1) * 4);
    int*   bbase   = (int*)  alloc((size_t)(NB + 1) * 4);
    int2*  cw      = (int2*) alloc((size_t)E * 8);
    const long NU64 = (long)NU * 64, NI64 = (long)NI * 64;
    const long tot = NU64 + NI64;          // = N*64
    u8* x1 = (u8*)alloc((size_t)tot);
    u8* x2 = (u8*)alloc((size_t)tot);
    u8* x3 = (u8*)alloc((size_t)tot);
    u8* x4 = (u8*)alloc((size_t)tot);

    // d_out scratch: x0 in [0, tot); u32 staging in [STG_OFF, STG_OFF + NB*STG_CAP*4).
    // Output buffer is provably 2*tot floats = 8*tot bytes (final_kernel writes exactly
    // that). NOTE: out_size is in ELEMENTS, not bytes (round-3 lesson) — do not gate on it.
    const size_t out_bytes = (size_t)tot * 8;   // 76.8 MB
    u8*       x0      = (u8*)out;
    unsigned* staging = (unsigned*)((char*)out + STG_OFF);

    detect_kernel<<<1, 256, 0, stream>>>(edges, flag);

    bool fast = (NB <= NB_MAX) && (N < (1 << 20)) &&
                (STG_OFF + (size_t)NB * STG_CAP * 4 <= out_bytes) &&
                ((size_t)tot <= STG_OFF);

    if (fast) {
        gcur_fixed_init<<<(NB + 255) / 256, 256, 0, stream>>>(gcur, NB);
        part1_kernel<<<(E + P1_CHUNK - 1) / P1_CHUNK, P1_T, 0, stream>>>(edges, flag, gcur,
                                                                         staging, E, NB);
        bucket_scan_kernel<<<1, 1024, 0, stream>>>(gcur, bbase, NB);
        part2a_kernel<<<NB, 256, 0, stream>>>(gcur, bbase, staging, row_ptr, dis, N, E, NB);
        part2b_kernel<<<NB, 256, 0, stream>>>(row_ptr, gcur, staging, dis, cw, N);
    } else {
        const int nb = (N + SCAN_B - 1) / SCAN_B;
        hipMemsetAsync(deg, 0, (size_t)N * 4, stream);
        count_deg_kernel<<<(E + 255) / 256, 256, 0, stream>>>(edges, flag, deg, E);
        scan_phase1<<<nb, SCAN_B, 0, stream>>>(deg, row_ptr, bsum, N);
        scan_phase2<<<1, 1024, 0, stream>>>(bsum, nb);
        scan_phase3<<<nb, SCAN_B, 0, stream>>>(deg, bsum, row_ptr, cursor, dis, N, E);
        scatter_kernel<<<(E + 255) / 256, 256, 0, stream>>>(edges, flag, dis, cursor, cw, E);
    }

    init_kernel<<<(int)((tot + 255) / 256), 256, 0, stream>>>(eu, ei, x0, NU64, tot);

    const int nblk = (N + 3) / 4;
    spmm_kernel<<<nblk, 256, 0, stream>>>(row_ptr, cw, x0, x1, N);
    spmm_kernel<<<nblk, 256, 0, stream>>>(row_ptr, cw, x1, x2, N);
    spmm_kernel<<<nblk, 256, 0, stream>>>(row_ptr, cw, x2, x3, N);
    spmm_kernel<<<nblk, 256, 0, stream>>>(row_ptr, cw, x3, x4, N);

    final_kernel<<<(int)((tot + 255) / 256), 256, 0, stream>>>(x1, x2, x3, x4, eu, ei,
                                                               out, NU64, NI64);
}

// Round 7
// 540.306 us; speedup vs baseline: 1.0642x; 1.0642x over previous
//
#include <hip/hip_runtime.h>
#include <hip/hip_fp8.h>

typedef unsigned char u8;
typedef float v2f __attribute__((ext_vector_type(2)));

#define SCAN_B 256

// bucketed scatter params
#define NPB      128          // dst nodes per bucket
#define NPB_SH   7
#define P2_CAP   6144         // win entries per bucket (48 KB LDS)
#define STG_CAP  6144         // fixed staging capacity per bucket (expected max ~5.4K)
#define P1_CHUNK 16384        // edges per part1 block: 489 blocks AND 14-entry runs
#define P1_T     256
#define P1_IT    (P1_CHUNK / P1_T)    // 64
#define NB_MAX   2048         // part1 LDS bucket capacity (NB=1172 for N=150K)
#define STG_OFF  ((size_t)10 << 20)   // staging offset in d_out (x0 uses [0, 9.6MB))

static __device__ __forceinline__ float fp8_to_f32(u8 b) {
    __hip_fp8_e4m3 t;
    t.__x = (__hip_fp8_storage_t)b;
    return (float)t;
}
static __device__ __forceinline__ u8 f32_to_fp8(float v) {
    __hip_fp8_e4m3 t(v);
    return (u8)t.__x;
}

// hardware packed fp8->f32 (2 values per instruction)
template <bool HI>
static __device__ __forceinline__ v2f pk2(unsigned w) {
#if __has_builtin(__builtin_amdgcn_cvt_pk_f32_fp8)
    return __builtin_amdgcn_cvt_pk_f32_fp8((int)w, HI);
#else
    v2f r;
    r.x = fp8_to_f32(HI ? (u8)(w >> 16) : (u8)(w));
    r.y = fp8_to_f32(HI ? (u8)(w >> 24) : (u8)(w >> 8));
    return r;
#endif
}

// ---------------- edge-format probe: int64-as-int32 (odd words zero) vs int32 ----------------
__global__ void detect_kernel(const int* __restrict__ edges, int* __restrict__ flag) {
    __shared__ int cnt[256];
    int t = threadIdx.x;
    int c = 0;
    for (int i = t; i < 32768; i += 256)
        if (edges[2 * i + 1] != 0) c++;
    cnt[t] = c;
    __syncthreads();
    for (int off = 128; off > 0; off >>= 1) {
        if (t < off) cnt[t] += cnt[t + off];
        __syncthreads();
    }
    if (t == 0) flag[0] = (cnt[0] < 8) ? 2 : 1;
}

// ---------------- fixed staging cursors: gcur[b] = b * STG_CAP ----------------
__global__ void gcur_fixed_init(int* __restrict__ gcur, int NB) {
    int b = blockIdx.x * blockDim.x + threadIdx.x;
    if (b < NB) gcur[b] = b * STG_CAP;
}

// ---------------- part1: partition edges into fixed-capacity dst-bucket regions --------
// 16K edges/block -> 489 blocks (all CUs busy) with ~14-entry (56B) runs per
// (block,bucket). 8-way manual unroll keeps 8 independent edge loads in flight per
// thread before the LDS atomics -> hides HBM/L3 latency at modest occupancy.
// Packed u32 staging entries (sv | dv_local<<20).
__global__ void part1_kernel(const int* __restrict__ edges, const int* __restrict__ flag,
                             int* __restrict__ gcur, unsigned* __restrict__ staging,
                             int E, int NB) {
    __shared__ int lcount[NB_MAX];
    __shared__ int lbase[NB_MAX];
    int t = threadIdx.x;
    int s = flag[0];
    long e0 = (long)blockIdx.x * P1_CHUNK;
    const int* dptr = edges + (long)E * s;   // dst stream base
    for (int b = t; b < NB; b += P1_T) lcount[b] = 0;
    __syncthreads();
    // count pass: 8 loads in flight per thread
    for (int j = 0; j < P1_IT; j += 8) {
        int dv[8]; bool vl[8];
        #pragma unroll
        for (int k = 0; k < 8; ++k) {
            long e = e0 + (long)(j + k) * P1_T + t;
            vl[k] = (e < E);
            dv[k] = vl[k] ? dptr[e * s] : 0;
        }
        #pragma unroll
        for (int k = 0; k < 8; ++k)
            if (vl[k]) atomicAdd(&lcount[dv[k] >> NPB_SH], 1);
    }
    __syncthreads();
    for (int b = t; b < NB; b += P1_T) {
        int c = lcount[b];
        lbase[b] = (c > 0) ? atomicAdd(&gcur[b], c) : 0;
        lcount[b] = 0;          // reuse as block-local cursor
    }
    __syncthreads();
    // scatter pass: 8 edges (16 loads) in flight per thread
    for (int j = 0; j < P1_IT; j += 8) {
        int dv[8], sv[8]; bool vl[8];
        #pragma unroll
        for (int k = 0; k < 8; ++k) {
            long e = e0 + (long)(j + k) * P1_T + t;
            vl[k] = (e < E);
            dv[k] = vl[k] ? dptr[e * s] : 0;
            sv[k] = vl[k] ? edges[e * s] : 0;
        }
        #pragma unroll
        for (int k = 0; k < 8; ++k) {
            if (vl[k]) {
                int b = dv[k] >> NPB_SH;
                int slot = atomicAdd(&lcount[b], 1);
                int pos = lbase[b] + slot;
                if (pos < (b + 1) * STG_CAP)        // overflow guard (never hit here)
                    staging[pos] = (unsigned)sv[k]
                                 | ((unsigned)(dv[k] & (NPB - 1)) << 20);
            }
        }
    }
}

// ---------------- bucket scan: bbase = excl-scan of (gcur[b] - b*STG_CAP) ----------------
__global__ void bucket_scan_kernel(const int* __restrict__ gcur, int* __restrict__ bbase,
                                   int NB) {
    __shared__ int sh[2][1024];
    int t = threadIdx.x;
    int i0 = 2 * t, i1 = 2 * t + 1;
    int a0 = (i0 < NB) ? (gcur[i0] - i0 * STG_CAP) : 0;
    int a1 = (i1 < NB) ? (gcur[i1] - i1 * STG_CAP) : 0;
    sh[0][t] = a0 + a1;
    __syncthreads();
    int src = 0;
    for (int off = 1; off < 1024; off <<= 1) {
        int x = sh[src][t] + ((t >= off) ? sh[src][t - off] : 0);
        sh[src ^ 1][t] = x;
        src ^= 1;
        __syncthreads();
    }
    int incl = sh[src][t];           // inclusive over pairs
    int excl = incl - (a0 + a1);
    if (i0 < NB) bbase[i0] = excl;
    if (i1 < NB) bbase[i1] = excl + a0;
    if (t == 1023) bbase[NB] = incl; // total == E
}

// ---------------- part2a: per-bucket node degrees -> row_ptr + dis (LDS only) ------------
__global__ void __launch_bounds__(256) part2a_kernel(
        const int* __restrict__ gcur, const int* __restrict__ bbase,
        const unsigned* __restrict__ staging, int* __restrict__ row_ptr,
        float* __restrict__ dis, int n, int E, int NB) {
    __shared__ int cnt[NPB];
    __shared__ int sc[2][NPB];
    int b = blockIdx.x;
    int t = threadIdx.x;
    int dlo = b << NPB_SH;
    int sbase = b * STG_CAP;
    int c = gcur[b] - sbase;         // edges in this bucket
    int base = bbase[b];             // CSR base of bucket
    if (t < NPB) cnt[t] = 0;
    __syncthreads();
    for (int k = t; k < c; k += 256) {
        unsigned wd = staging[sbase + k];
        atomicAdd(&cnt[wd >> 20], 1);
    }
    __syncthreads();
    if (t < NPB) sc[0][t] = cnt[t];
    __syncthreads();
    int src = 0;
    for (int off = 1; off < NPB; off <<= 1) {
        if (t < NPB) {
            int x = sc[src][t] + ((t >= off) ? sc[src][t - off] : 0);
            sc[src ^ 1][t] = x;
        }
        src ^= 1;
        __syncthreads();
    }
    if (t < NPB) {
        int node = dlo + t;
        if (node < n) {
            int d = cnt[t];
            row_ptr[node] = base + sc[src][t] - d;   // exclusive
            dis[node] = (d > 0) ? rsqrtf((float)d) : 0.0f;
        }
    }
    if (b == 0 && t == 0) row_ptr[n] = E;
}

// ---------------- part2b: per-bucket exact CSR placement, built in LDS ----------------
__global__ void __launch_bounds__(256) part2b_kernel(
        const int* __restrict__ row_ptr, const int* __restrict__ gcur,
        const unsigned* __restrict__ staging, const float* __restrict__ dis,
        int2* __restrict__ cw, int n) {
    __shared__ int2 win[P2_CAP];
    __shared__ int cur[NPB];
    int b = blockIdx.x;
    int t = threadIdx.x;
    int dlo = b << NPB_SH;
    int sbase = b * STG_CAP;
    int cnt = gcur[b] - sbase;
    int base = row_ptr[dlo];
    if (t < NPB) {
        int node = dlo + t;
        cur[t] = (node < n) ? (row_ptr[node] - base) : 0;
    }
    __syncthreads();
    if (cnt <= P2_CAP) {
        for (int k = t; k < cnt; k += 256) {
            unsigned wd = staging[sbase + k];
            int sv = wd & 0xFFFFF;
            int dloc = wd >> 20;
            float w = dis[sv] * dis[dlo + dloc];
            int p = atomicAdd(&cur[dloc], 1);
            win[p] = make_int2(sv, __float_as_int(w));
        }
        __syncthreads();
        for (int k = t; k < cnt; k += 256)
            cw[base + k] = win[k];
    } else {
        for (int k = t; k < cnt; k += 256) {
            unsigned wd = staging[sbase + k];
            int sv = wd & 0xFFFFF;
            int dloc = wd >> 20;
            float w = dis[sv] * dis[dlo + dloc];
            int p = atomicAdd(&cur[dloc], 1);
            cw[base + p] = make_int2(sv, __float_as_int(w));
        }
    }
}

// ================= legacy fallback path (NB > NB_MAX / N too big / staging misfit) =======
__global__ void count_deg_kernel(const int* __restrict__ edges, const int* __restrict__ flag,
                                 int* __restrict__ deg, int E) {
    int e = blockIdx.x * blockDim.x + threadIdx.x;
    if (e >= E) return;
    int s = flag[0];
    int d = edges[(long)E * s + (long)e * s];
    atomicAdd(&deg[d], 1);
}

__global__ void scan_phase1(const int* __restrict__ deg, int* __restrict__ row_ptr,
                            int* __restrict__ bsum, int n) {
    __shared__ int sh[2][SCAN_B];
    int t = threadIdx.x;
    int gi = blockIdx.x * SCAN_B + t;
    int v = (gi < n) ? deg[gi] : 0;
    int src = 0;
    sh[0][t] = v;
    __syncthreads();
    for (int off = 1; off < SCAN_B; off <<= 1) {
        int x = sh[src][t] + ((t >= off) ? sh[src][t - off] : 0);
        sh[src ^ 1][t] = x;
        src ^= 1;
        __syncthreads();
    }
    int incl = sh[src][t];
    if (gi < n) row_ptr[gi] = incl - v;
    if (t == SCAN_B - 1) bsum[blockIdx.x] = incl;
}

__global__ void scan_phase2(int* __restrict__ bsum, int nb) {
    __shared__ int sh[1024];
    int t = threadIdx.x;
    sh[t] = (t < nb) ? bsum[t] : 0;
    __syncthreads();
    if (t == 0) {
        int acc = 0;
        for (int i = 0; i < nb; ++i) { int x = sh[i]; sh[i] = acc; acc += x; }
    }
    __syncthreads();
    if (t < nb) bsum[t] = sh[t];
}

__global__ void scan_phase3(const int* __restrict__ deg, const int* __restrict__ bsum,
                            int* __restrict__ row_ptr, int* __restrict__ cursor,
                            float* __restrict__ dis, int n, int E) {
    int gi = blockIdx.x * SCAN_B + threadIdx.x;
    if (gi < n) {
        int e = row_ptr[gi] + bsum[blockIdx.x];
        row_ptr[gi] = e;
        cursor[gi]  = e;
        int d = deg[gi];
        dis[gi] = (d > 0) ? rsqrtf((float)d) : 0.0f;
    }
    if (gi == 0) row_ptr[n] = E;
}

__global__ void scatter_kernel(const int* __restrict__ edges, const int* __restrict__ flag,
                               const float* __restrict__ dis, int* __restrict__ cursor,
                               int2* __restrict__ cw, int E) {
    int e = blockIdx.x * blockDim.x + threadIdx.x;
    if (e >= E) return;
    int s = flag[0];
    int sv = edges[(long)e * s];
    int dv = edges[(long)E * s + (long)e * s];
    float w = dis[sv] * dis[dv];
    int pos = atomicAdd(&cursor[dv], 1);
    cw[pos] = make_int2(sv, __float_as_int(w));
}
// ================= end legacy =================

// ---------------- init: x0 (fp8, in d_out scratch) = emb ----------------
__global__ void init_kernel(const float* __restrict__ eu, const float* __restrict__ ei,
                            u8* __restrict__ x0, long NU64, long tot) {
    long i = (long)blockIdx.x * blockDim.x + threadIdx.x;
    if (i >= tot) return;
    float v = (i < NU64) ? eu[i] : ei[i - NU64];
    x0[i] = f32_to_fp8(v);
}

// ---------------- SpMM layer: one wave per dst node, 8 edges per gather instruction ------
// g = lane>>3 selects one of 8 edge slots, h = lane&7 the dim-octet (dims 8h..8h+7, one
// dwordx2 of fp8). Each gather instruction serves 8 edges (512B across 8 lines).
__global__ void spmm_kernel(const int* __restrict__ row_ptr, const int2* __restrict__ cw,
                            const u8* __restrict__ xin, u8* __restrict__ xout, int n) {
    int wave = (blockIdx.x * blockDim.x + threadIdx.x) >> 6;
    int lane = threadIdx.x & 63;
    if (wave >= n) return;
    int beg = row_ptr[wave], end = row_ptr[wave + 1];
    int g = lane >> 3;      // edge slot 0..7
    int h = lane & 7;       // dim octet

    float a0 = 0.f, a1 = 0.f, a2 = 0.f, a3 = 0.f;
    float a4 = 0.f, a5 = 0.f, a6 = 0.f, a7 = 0.f;

    for (int iA = beg + g; iA < end; iA += 16) {
        int iB = iA + 8;
        bool vB = iB < end;

        int2 ca = cw[iA];
        int2 cb = cw[vB ? iB : iA];

        uint2 dA = *(const uint2*)(xin + ((long)ca.x << 6) + (h << 3));
        uint2 dB = *(const uint2*)(xin + ((long)cb.x << 6) + (h << 3));

        float wA = __int_as_float(ca.y);
        float wB = vB ? __int_as_float(cb.y) : 0.0f;

        v2f pA0 = pk2<false>(dA.x), pA1 = pk2<true>(dA.x);
        v2f pA2 = pk2<false>(dA.y), pA3 = pk2<true>(dA.y);
        v2f pB0 = pk2<false>(dB.x), pB1 = pk2<true>(dB.x);
        v2f pB2 = pk2<false>(dB.y), pB3 = pk2<true>(dB.y);

        a0 = fmaf(wA, pA0.x, a0); a1 = fmaf(wA, pA0.y, a1);
        a2 = fmaf(wA, pA1.x, a2); a3 = fmaf(wA, pA1.y, a3);
        a4 = fmaf(wA, pA2.x, a4); a5 = fmaf(wA, pA2.y, a5);
        a6 = fmaf(wA, pA3.x, a6); a7 = fmaf(wA, pA3.y, a7);
        a0 = fmaf(wB, pB0.x, a0); a1 = fmaf(wB, pB0.y, a1);
        a2 = fmaf(wB, pB1.x, a2); a3 = fmaf(wB, pB1.y, a3);
        a4 = fmaf(wB, pB2.x, a4); a5 = fmaf(wB, pB2.y, a5);
        a6 = fmaf(wB, pB3.x, a6); a7 = fmaf(wB, pB3.y, a7);
    }

    a0 += __shfl_xor(a0, 8);  a1 += __shfl_xor(a1, 8);
    a2 += __shfl_xor(a2, 8);  a3 += __shfl_xor(a3, 8);
    a4 += __shfl_xor(a4, 8);  a5 += __shfl_xor(a5, 8);
    a6 += __shfl_xor(a6, 8);  a7 += __shfl_xor(a7, 8);
    a0 += __shfl_xor(a0, 16); a1 += __shfl_xor(a1, 16);
    a2 += __shfl_xor(a2, 16); a3 += __shfl_xor(a3, 16);
    a4 += __shfl_xor(a4, 16); a5 += __shfl_xor(a5, 16);
    a6 += __shfl_xor(a6, 16); a7 += __shfl_xor(a7, 16);
    a0 += __shfl_xor(a0, 32); a1 += __shfl_xor(a1, 32);
    a2 += __shfl_xor(a2, 32); a3 += __shfl_xor(a3, 32);
    a4 += __shfl_xor(a4, 32); a5 += __shfl_xor(a5, 32);
    a6 += __shfl_xor(a6, 32); a7 += __shfl_xor(a7, 32);

    if (g == 0) {
        unsigned lo = (unsigned)f32_to_fp8(a0)
                    | ((unsigned)f32_to_fp8(a1) << 8)
                    | ((unsigned)f32_to_fp8(a2) << 16)
                    | ((unsigned)f32_to_fp8(a3) << 24);
        unsigned hi = (unsigned)f32_to_fp8(a4)
                    | ((unsigned)f32_to_fp8(a5) << 8)
                    | ((unsigned)f32_to_fp8(a6) << 16)
                    | ((unsigned)f32_to_fp8(a7) << 24);
        *(uint2*)(xout + ((long)wave << 6) + (h << 3)) = make_uint2(lo, hi);
    }
}

// ---------------- epilogue ----------------
__global__ void final_kernel(const u8* __restrict__ x1, const u8* __restrict__ x2,
                             const u8* __restrict__ x3, const u8* __restrict__ x4,
                             const float* __restrict__ eu, const float* __restrict__ ei,
                             float* __restrict__ out, long NU64, long NI64) {
    long i = (long)blockIdx.x * blockDim.x + threadIdx.x;
    if (i >= NU64 + NI64) return;
    float base = (i < NU64) ? eu[i] : ei[i - NU64];
    float s = base + fp8_to_f32(x1[i]) + fp8_to_f32(x2[i])
                   + fp8_to_f32(x3[i]) + fp8_to_f32(x4[i]);
    float v = s * (1.0f / 25.0f);
    if (i < NU64) {
        out[i] = v;
        out[NU64 + i] = base;
    } else {
        long j = i - NU64;
        out[2 * NU64 + j] = v;
        out[2 * NU64 + NI64 + j] = base;
    }
}

extern "C" void kernel_launch(void* const* d_in, const int* in_sizes, int n_in,
                              void* d_out, int out_size, void* d_ws, size_t ws_size,
                              hipStream_t stream) {
    const float* eu = (const float*)d_in[0];
    const float* ei = (const float*)d_in[1];
    const int* edges = (const int*)d_in[2];
    float* out = (float*)d_out;

    const int NU = in_sizes[0] / 64;
    const int NI = in_sizes[1] / 64;
    const int N  = NU + NI;
    const int E  = in_sizes[2] / 2;
    const int NB = (N + NPB - 1) / NPB;     // 1172 for N=150K

    // workspace carve-up (256B aligned)
    char* w = (char*)d_ws;
    size_t off = 0;
    auto alloc = [&](size_t bytes) -> void* {
        void* p = w + off;
        off += (bytes + 255) & ~(size_t)255;
        return p;
    };
    int*   flag    = (int*)  alloc(256);
    int*   deg     = (int*)  alloc((size_t)N * 4);        // legacy path only
    int*   row_ptr = (int*)  alloc((size_t)(N + 1) * 4);
    int*   cursor  = (int*)  alloc((size_t)N * 4);        // legacy path only
    float* dis     = (float*)alloc((size_t)N * 4);
    int*   bsum    = (int*)  alloc(1024 * 4);             // legacy path only
    int*   gcur    = (int*)  alloc((size_t)(NB + 1) * 4);
    int*   bbase   = (int*)  alloc((size_t)(NB + 1) * 4);
    int2*  cw      = (int2*) alloc((size_t)E * 8);
    const long NU64 = (long)NU * 64, NI64 = (long)NI * 64;
    const long tot = NU64 + NI64;          // = N*64
    u8* x1 = (u8*)alloc((size_t)tot);
    u8* x2 = (u8*)alloc((size_t)tot);
    u8* x3 = (u8*)alloc((size_t)tot);
    u8* x4 = (u8*)alloc((size_t)tot);

    // d_out scratch: x0 in [0, tot); u32 staging in [STG_OFF, STG_OFF + NB*STG_CAP*4).
    // Output buffer is provably 2*tot floats = 8*tot bytes (final_kernel writes exactly
    // that). NOTE: out_size is in ELEMENTS, not bytes (round-3 lesson) — do not gate on it.
    const size_t out_bytes = (size_t)tot * 8;   // 76.8 MB
    u8*       x0      = (u8*)out;
    unsigned* staging = (unsigned*)((char*)out + STG_OFF);

    detect_kernel<<<1, 256, 0, stream>>>(edges, flag);

    bool fast = (NB <= NB_MAX) && (N < (1 << 20)) &&
                (STG_OFF + (size_t)NB * STG_CAP * 4 <= out_bytes) &&
                ((size_t)tot <= STG_OFF);

    if (fast) {
        gcur_fixed_init<<<(NB + 255) / 256, 256, 0, stream>>>(gcur, NB);
        part1_kernel<<<(E + P1_CHUNK - 1) / P1_CHUNK, P1_T, 0, stream>>>(edges, flag, gcur,
                                                                         staging, E, NB);
        bucket_scan_kernel<<<1, 1024, 0, stream>>>(gcur, bbase, NB);
        part2a_kernel<<<NB, 256, 0, stream>>>(gcur, bbase, staging, row_ptr, dis, N, E, NB);
        part2b_kernel<<<NB, 256, 0, stream>>>(row_ptr, gcur, staging, dis, cw, N);
    } else {
        const int nb = (N + SCAN_B - 1) / SCAN_B;
        hipMemsetAsync(deg, 0, (size_t)N * 4, stream);
        count_deg_kernel<<<(E + 255) / 256, 256, 0, stream>>>(edges, flag, deg, E);
        scan_phase1<<<nb, SCAN_B, 0, stream>>>(deg, row_ptr, bsum, N);
        scan_phase2<<<1, 1024, 0, stream>>>(bsum, nb);
        scan_phase3<<<nb, SCAN_B, 0, stream>>>(deg, bsum, row_ptr, cursor, dis, N, E);
        scatter_kernel<<<(E + 255) / 256, 256, 0, stream>>>(edges, flag, dis, cursor, cw, E);
    }

    init_kernel<<<(int)((tot + 255) / 256), 256, 0, stream>>>(eu, ei, x0, NU64, tot);

    const int nblk = (N + 3) / 4;
    spmm_kernel<<<nblk, 256, 0, stream>>>(row_ptr, cw, x0, x1, N);
    spmm_kernel<<<nblk, 256, 0, stream>>>(row_ptr, cw, x1, x2, N);
    spmm_kernel<<<nblk, 256, 0, stream>>>(row_ptr, cw, x2, x3, N);
    spmm_kernel<<<nblk, 256, 0, stream>>>(row_ptr, cw, x3, x4, N);

    final_kernel<<<(int)((tot + 255) / 256), 256, 0, stream>>>(x1, x2, x3, x4, eu, ei,
                                                               out, NU64, NI64);
}